// Round 3
// baseline (114.562 us; speedup 1.0000x reference)
//
#include <hip/hip_runtime.h>

// Non-backtracking random walk, 32 steps.
// out = [walks (steps+1,n) ; walk_edges (steps,n)] int32.
//
// R11: direct-gather walker. R10 proved the 256 MiB ws poison fill
// (~44 us) is unconditional harness behavior — not removable. Remaining
// lever is our pipeline. Walker was L2-request-throughput bound at
// 2 gathers/walk/step (u16 entry + u16 hbits, two instructions). Key
// observation: adj_nodes is already the ideal gather table — 64 B/row =
// exactly one 64B cache line, u32 ids, no hbit needed. Direct gather =
// 1 request/walk/step (predicated alt hits the SAME line). Trade: 6.4 MB
// table > 4 MiB/XCD L2 (~60% hit, L3-resident backing) vs halved request
// count + deleted pack stage (no 4.6 MB table write, check-only kernel)
// + memset dispatch replaced by an epoch sentinel. Walker control flow
// otherwise BIT-IDENTICAL to the verified R8/R10 structure (2 chains,
// predicated alt, nontemporal stores).

#define DEG 16
#define CHAINS 2

// Epoch-tagged bad-input flag. Zero-initialized at module load. check_kernel
// stores the current epoch iff the CSR is non-uniform; walker takes the fast
// path iff g_flag != epoch. No memset needed; correct under graph replay
// (inputs are immutable per captured graph, so badness is constant).
__device__ int g_flag;

__global__ __launch_bounds__(256) void check_kernel(
    const int* __restrict__ adj_offset,
    const int* __restrict__ degrees,
    int n, int epoch) {
    int v = blockIdx.x * blockDim.x + threadIdx.x;
    if (v >= n) return;
    if (degrees[v] != DEG || adj_offset[v] != v * DEG)
        g_flag = epoch;
}

template <int STEPS>
__global__ __launch_bounds__(64) void walker_fast3(
    const int* __restrict__ adj_nodes,
    const int* __restrict__ choices,
    int* __restrict__ out, int n, int h, int epoch,
    const int* __restrict__ adj_offset,
    const int* __restrict__ degrees) {

    int t = blockIdx.x * blockDim.x + threadIdx.x;
    if (t >= h) return;

    int* walks      = out;                    // [STEPS+1, n]
    int* walk_edges = out + (STEPS + 1) * n;  // [STEPS, n]

    int w0 = t;
    int w1 = t + h;
    bool has1 = (w1 < n);
    int w1s = has1 ? w1 : w0;

    __builtin_nontemporal_store(w0, &walks[w0]);
    if (has1) __builtin_nontemporal_store(w1, &walks[w1]);

    if (g_flag != epoch) {
        // ---- fast path: uniform CSR deg=16, direct 1-line gathers ----
        int c0[STEPS], c1[STEPS];
#pragma unroll
        for (int i = 0; i < STEPS; ++i) {
            c0[i] = __builtin_nontemporal_load(&choices[i * n + w0]);
            c1[i] = __builtin_nontemporal_load(&choices[i * n + w1s]);
        }

        int prev0 = -1, cur0 = w0;
        int prev1 = -1, cur1 = w1s;
#pragma unroll
        for (int i = 0; i < STEPS; ++i) {
            unsigned ch0 = (unsigned)c0[i];
            unsigned ch1 = (unsigned)c1[i];
            unsigned e0 = ch0 & (DEG - 1);
            unsigned e1 = ch1 & (DEG - 1);

            const int* r0 = adj_nodes + ((unsigned)cur0 << 4);
            const int* r1 = adj_nodes + ((unsigned)cur1 << 4);

            // two unconditional gathers (1 per chain), issued together;
            // each touches exactly one 64B line (the whole row)
            int n00 = r0[e0];
            int n10 = r1[e1];

            int nw0 = n00, nw1 = n10;
            unsigned ef0 = e0, ef1 = e1;
            // predicated alt gathers: same line as the first gather
            if (n00 == prev0) {
                unsigned a0 = (e0 + 1u + ch0 % (DEG - 1)) & (DEG - 1);
                nw0 = r0[a0];
                ef0 = a0;
            }
            if (n10 == prev1) {
                unsigned a1 = (e1 + 1u + ch1 % (DEG - 1)) & (DEG - 1);
                nw1 = r1[a1];
                ef1 = a1;
            }

            int ce0 = (cur0 << 4) + (int)ef0;
            int ce1 = (cur1 << 4) + (int)ef1;

            __builtin_nontemporal_store(nw0, &walks[(i + 1) * n + w0]);
            __builtin_nontemporal_store(ce0, &walk_edges[i * n + w0]);
            if (has1) {
                __builtin_nontemporal_store(nw1, &walks[(i + 1) * n + w1]);
                __builtin_nontemporal_store(ce1, &walk_edges[i * n + w1]);
            }
            prev0 = cur0; cur0 = nw0;
            prev1 = cur1; cur1 = nw1;
        }
    } else {
        // ---- general fallback: 2 dependent gathers/step ----
        for (int k = 0; k < 2; ++k) {
            int w = (k == 0) ? w0 : w1;
            if (w >= n) break;
            int prev = -1, cur = w;
            for (int i = 0; i < STEPS; ++i) {
                int chv = choices[i * n + w];
                int deg = degrees[cur];
                int off = adj_offset[cur];
                int nb  = deg - 1 > 1 ? deg - 1 : 1;

                int e      = chv % deg;
                int chosen = off + e;
                int alt    = off + (e + 1 + chv % nb) % deg;

                int nv0 = adj_nodes[chosen];
                int nv1 = adj_nodes[alt];

                bool bt = (nv0 == prev);
                int nw  = bt ? nv1 : nv0;
                walks[(i + 1) * n + w] = nw;
                walk_edges[i * n + w]  = bt ? alt : chosen;
                prev = cur;
                cur  = nw;
            }
        }
    }
}

__global__ __launch_bounds__(256) void walker_generic(
    const int* __restrict__ adj_nodes,
    const int* __restrict__ adj_offset,
    const int* __restrict__ degrees,
    const int* __restrict__ choices,
    int* __restrict__ out, int n, int steps) {

    int w = blockIdx.x * blockDim.x + threadIdx.x;
    if (w >= n) return;

    int* walks      = out;
    int* walk_edges = out + (steps + 1) * n;
    walks[w] = w;

    int prev = -1, cur = w;
    for (int i = 0; i < steps; ++i) {
        int chv = choices[i * n + w];
        int deg = degrees[cur];
        int off = adj_offset[cur];
        int nb  = deg - 1 > 1 ? deg - 1 : 1;

        int e      = chv % deg;
        int chosen = off + e;
        int alt    = off + (e + 1 + chv % nb) % deg;

        int nv0 = adj_nodes[chosen];
        int nv1 = adj_nodes[alt];

        bool bt = (nv0 == prev);
        int nw  = bt ? nv1 : nv0;
        walks[(i + 1) * n + w] = nw;
        walk_edges[i * n + w]  = bt ? alt : chosen;
        prev = cur;
        cur  = nw;
    }
}

extern "C" void kernel_launch(void* const* d_in, const int* in_sizes, int n_in,
                              void* d_out, int out_size, void* d_ws, size_t ws_size,
                              hipStream_t stream) {
    // inputs: 0=x (unused), 1=adj_nodes, 2=adj_offset, 3=degrees, 4=choices
    const int* adj_nodes  = (const int*)d_in[1];
    const int* adj_offset = (const int*)d_in[2];
    const int* degrees    = (const int*)d_in[3];
    const int* choices    = (const int*)d_in[4];
    int* out = (int*)d_out;

    int n     = in_sizes[2];
    int steps = in_sizes[4] / n;

    if (steps == 32) {
        static int s_epoch = 0;
        int epoch = ++s_epoch;   // baked into a captured graph; see g_flag note

        int pg = (n + 255) / 256;
        check_kernel<<<pg, 256, 0, stream>>>(adj_offset, degrees, n, epoch);

        int h  = (n + CHAINS - 1) / CHAINS;
        int wb = 64, wg = (h + wb - 1) / wb;
        walker_fast3<32><<<wg, wb, 0, stream>>>(adj_nodes, choices, out, n, h,
                                                epoch, adj_offset, degrees);
    } else {
        int block = 256, grid = (n + block - 1) / block;
        walker_generic<<<grid, block, 0, stream>>>(adj_nodes, adj_offset,
                                                   degrees, choices, out, n, steps);
    }
}

// Round 4
// 104.942 us; speedup vs baseline: 1.0917x; 1.0917x over previous
//
#include <hip/hip_runtime.h>

// Non-backtracking random walk, 32 steps.
// out = [walks (steps+1,n) ; walk_edges (steps,n)] int32.
//
// R12: single-load L2-resident format. R11 refuted "requests are all that
// matters": 1 req/step from the 64B/row (6.4MB) table LOST to 2 req/step
// from the 36B/row (3.6MB) L2-resident table -> L2 residency dominates.
// This round gets BOTH: 18-bit bit-packed entries, 36B/row (3.6MB,
// L2-resident), decoded with ONE global_load_dwordx2 (GCN/CDNA VMEM
// multi-dword loads need only 4B alignment) + v_alignbit_b32 funnel shift.
// 1 VMEM instr/walk/step vs R8's 2 (entry+hbits). The 4B-aligned-dwordx2
// assumption is guarded by a validate kernel that decodes every row via the
// exact walker path and compares vs adj_nodes; mismatch -> epoch flag ->
// general fallback (slow but correct). Memset dispatch replaced by the
// epoch sentinel (R11). Pack flush keeps R10's verified 576-uint4 bound.

#define DEG 16
#define CHAINS 2
#define NMAX 131072          // row-count limit of the packed table
#define PACK_BLOCK 256
#define ENT_MASK 0x3FFFFu    // 18-bit entries

// Packed adjacency: 9 dwords/row = 16 x 18-bit entries, +2 dwords pad so
// entry 15's dwordx2 (dwords 8,9) of the last row stays in-bounds.
__device__ unsigned int g_pk32[(size_t)NMAX * 9 + 2];
__device__ int g_flag;   // == epoch  =>  take the general fallback

__global__ __launch_bounds__(PACK_BLOCK) void pack_check_kernel(
    const int* __restrict__ adj_nodes,
    const int* __restrict__ adj_offset,
    const int* __restrict__ degrees,
    int n, int epoch) {
    __shared__ __align__(16) unsigned int lds[PACK_BLOCK * 9];

    int tid = threadIdx.x;
    int blockStart = blockIdx.x * PACK_BLOCK;
    int v = blockStart + tid;

    bool bad = false;
    if (v < n) {
        bad = (degrees[v] != DEG) || (adj_offset[v] != v * DEG);

        const uint4* row4 = (const uint4*)(adj_nodes + (size_t)v * DEG); // 64B-aligned
        uint4 r[4];
        r[0] = row4[0]; r[1] = row4[1]; r[2] = row4[2]; r[3] = row4[3];
        const unsigned* rr = (const unsigned*)r;

        unsigned dw[9];
#pragma unroll
        for (int j = 0; j < 9; ++j) dw[j] = 0u;
#pragma unroll
        for (int e = 0; e < 16; ++e) {
            unsigned id = rr[e];
            if (id >= 262144u) bad = true;            // needs >18 bits
            unsigned s   = 18u * (unsigned)e;
            unsigned d   = s >> 5;
            unsigned off = s & 31u;
            dw[d] |= id << off;
            if (off > 14u) dw[d + 1] |= id >> (32u - off);  // field crosses dword
        }
#pragma unroll
        for (int j = 0; j < 9; ++j) lds[tid * 9 + j] = dw[j];
    }
    __syncthreads();

    // coalesced flush: 256 rows * 9 dwords = 2304 dwords = 576 uint4
    int rows = n - blockStart;
    if (rows > PACK_BLOCK) rows = PACK_BLOCK;
    unsigned int* dstBase = g_pk32 + (size_t)blockStart * 9;   // 16B-aligned (9216B/block)
    if (rows == PACK_BLOCK) {
        uint4* dst4 = (uint4*)dstBase;
        const uint4* src4 = (const uint4*)lds;
        for (int i = tid; i < (PACK_BLOCK * 9) / 4; i += PACK_BLOCK)
            dst4[i] = src4[i];
    } else {
        int ndw = rows * 9;
        for (int i = tid; i < ndw; i += PACK_BLOCK) dstBase[i] = lds[i];
    }

    if (bad) g_flag = epoch;
}

// Decode every entry of every row through the EXACT walker load path
// (4B-aligned dwordx2 + alignbit) and compare vs adj_nodes. Guards the
// one untested HW assumption; mismatch -> fallback, not failure.
__global__ __launch_bounds__(256) void validate_kernel(
    const int* __restrict__ adj_nodes, int n, int epoch) {
    int v = blockIdx.x * blockDim.x + threadIdx.x;
    if (v >= n) return;
    const unsigned* row = g_pk32 + (size_t)v * 9;
    bool bad = false;
#pragma unroll
    for (int e = 0; e < 16; ++e) {
        unsigned s   = 18u * (unsigned)e;
        unsigned d   = s >> 5;
        unsigned off = s & 31u;
        uint2 q = *(const uint2*)(row + d);     // dwordx2 at 4B alignment
        unsigned id = __builtin_amdgcn_alignbit(q.y, q.x, off) & ENT_MASK;
        if (id != (unsigned)adj_nodes[(size_t)v * DEG + e]) bad = true;
    }
    if (bad) g_flag = epoch;
}

template <int STEPS>
__global__ __launch_bounds__(64) void walker_fast4(
    const int* __restrict__ choices,
    int* __restrict__ out, int n, int h, int epoch,
    const int* __restrict__ adj_nodes,
    const int* __restrict__ adj_offset,
    const int* __restrict__ degrees) {

    int t = blockIdx.x * blockDim.x + threadIdx.x;
    if (t >= h) return;

    int* walks      = out;                    // [STEPS+1, n]
    int* walk_edges = out + (STEPS + 1) * n;  // [STEPS, n]

    int w0 = t;
    int w1 = t + h;
    bool has1 = (w1 < n);
    int w1s = has1 ? w1 : w0;

    __builtin_nontemporal_store(w0, &walks[w0]);
    if (has1) __builtin_nontemporal_store(w1, &walks[w1]);

    if (g_flag != epoch) {
        // ---- fast path: uniform CSR deg=16, one dwordx2 gather per step ----
        int c0[STEPS], c1[STEPS];
#pragma unroll
        for (int i = 0; i < STEPS; ++i) {
            c0[i] = __builtin_nontemporal_load(&choices[i * n + w0]);
            c1[i] = __builtin_nontemporal_load(&choices[i * n + w1s]);
        }

        int prev0 = -1, cur0 = w0;
        int prev1 = -1, cur1 = w1s;
#pragma unroll
        for (int i = 0; i < STEPS; ++i) {
            unsigned ch0 = (unsigned)c0[i];
            unsigned ch1 = (unsigned)c1[i];
            unsigned e0 = ch0 & (DEG - 1);
            unsigned e1 = ch1 & (DEG - 1);

            const unsigned* row0 = g_pk32 + (size_t)(unsigned)cur0 * 9u;
            const unsigned* row1 = g_pk32 + (size_t)(unsigned)cur1 * 9u;

            unsigned s0 = 18u * e0, d0 = s0 >> 5, f0 = s0 & 31u;
            unsigned s1 = 18u * e1, d1 = s1 >> 5, f1 = s1 & 31u;

            // two unconditional gathers (1 per chain), issued together
            uint2 q0 = *(const uint2*)(row0 + d0);
            uint2 q1 = *(const uint2*)(row1 + d1);

            int n00 = (int)(__builtin_amdgcn_alignbit(q0.y, q0.x, f0) & ENT_MASK);
            int n10 = (int)(__builtin_amdgcn_alignbit(q1.y, q1.x, f1) & ENT_MASK);

            int nw0 = n00, nw1 = n10;
            unsigned ef0 = e0, ef1 = e1;
            // predicated alt gathers: same row, ~2-4 lanes/wave
            if (n00 == prev0) {
                unsigned a0 = (e0 + 1u + ch0 % (DEG - 1)) & (DEG - 1);
                unsigned sa = 18u * a0, da = sa >> 5, fa = sa & 31u;
                uint2 qa = *(const uint2*)(row0 + da);
                nw0 = (int)(__builtin_amdgcn_alignbit(qa.y, qa.x, fa) & ENT_MASK);
                ef0 = a0;
            }
            if (n10 == prev1) {
                unsigned a1 = (e1 + 1u + ch1 % (DEG - 1)) & (DEG - 1);
                unsigned sb = 18u * a1, db = sb >> 5, fb = sb & 31u;
                uint2 qb = *(const uint2*)(row1 + db);
                nw1 = (int)(__builtin_amdgcn_alignbit(qb.y, qb.x, fb) & ENT_MASK);
                ef1 = a1;
            }

            int ce0 = (cur0 << 4) + (int)ef0;
            int ce1 = (cur1 << 4) + (int)ef1;

            __builtin_nontemporal_store(nw0, &walks[(i + 1) * n + w0]);
            __builtin_nontemporal_store(ce0, &walk_edges[i * n + w0]);
            if (has1) {
                __builtin_nontemporal_store(nw1, &walks[(i + 1) * n + w1]);
                __builtin_nontemporal_store(ce1, &walk_edges[i * n + w1]);
            }
            prev0 = cur0; cur0 = nw0;
            prev1 = cur1; cur1 = nw1;
        }
    } else {
        // ---- general fallback: 2 dependent gathers/step ----
        for (int k = 0; k < 2; ++k) {
            int w = (k == 0) ? w0 : w1;
            if (w >= n) break;
            int prev = -1, cur = w;
            for (int i = 0; i < STEPS; ++i) {
                int chv = choices[i * n + w];
                int deg = degrees[cur];
                int off = adj_offset[cur];
                int nb  = deg - 1 > 1 ? deg - 1 : 1;

                int e      = chv % deg;
                int chosen = off + e;
                int alt    = off + (e + 1 + chv % nb) % deg;

                int nv0 = adj_nodes[chosen];
                int nv1 = adj_nodes[alt];

                bool bt = (nv0 == prev);
                int nw  = bt ? nv1 : nv0;
                walks[(i + 1) * n + w] = nw;
                walk_edges[i * n + w]  = bt ? alt : chosen;
                prev = cur;
                cur  = nw;
            }
        }
    }
}

__global__ __launch_bounds__(256) void walker_generic(
    const int* __restrict__ adj_nodes,
    const int* __restrict__ adj_offset,
    const int* __restrict__ degrees,
    const int* __restrict__ choices,
    int* __restrict__ out, int n, int steps) {

    int w = blockIdx.x * blockDim.x + threadIdx.x;
    if (w >= n) return;

    int* walks      = out;
    int* walk_edges = out + (steps + 1) * n;
    walks[w] = w;

    int prev = -1, cur = w;
    for (int i = 0; i < steps; ++i) {
        int chv = choices[i * n + w];
        int deg = degrees[cur];
        int off = adj_offset[cur];
        int nb  = deg - 1 > 1 ? deg - 1 : 1;

        int e      = chv % deg;
        int chosen = off + e;
        int alt    = off + (e + 1 + chv % nb) % deg;

        int nv0 = adj_nodes[chosen];
        int nv1 = adj_nodes[alt];

        bool bt = (nv0 == prev);
        int nw  = bt ? nv1 : nv0;
        walks[(i + 1) * n + w] = nw;
        walk_edges[i * n + w]  = bt ? alt : chosen;
        prev = cur;
        cur  = nw;
    }
}

extern "C" void kernel_launch(void* const* d_in, const int* in_sizes, int n_in,
                              void* d_out, int out_size, void* d_ws, size_t ws_size,
                              hipStream_t stream) {
    // inputs: 0=x (unused), 1=adj_nodes, 2=adj_offset, 3=degrees, 4=choices
    const int* adj_nodes  = (const int*)d_in[1];
    const int* adj_offset = (const int*)d_in[2];
    const int* degrees    = (const int*)d_in[3];
    const int* choices    = (const int*)d_in[4];
    int* out = (int*)d_out;

    int n     = in_sizes[2];
    int steps = in_sizes[4] / n;

    if (steps == 32 && n <= NMAX) {
        static int s_epoch = 0;
        int epoch = ++s_epoch;   // baked into a captured graph; pack/validate
                                 // rerun per replay, badness is input-constant

        int pg = (n + PACK_BLOCK - 1) / PACK_BLOCK;
        pack_check_kernel<<<pg, PACK_BLOCK, 0, stream>>>(adj_nodes, adj_offset,
                                                         degrees, n, epoch);
        validate_kernel<<<pg, PACK_BLOCK, 0, stream>>>(adj_nodes, n, epoch);

        int h  = (n + CHAINS - 1) / CHAINS;
        int wb = 64, wg = (h + wb - 1) / wb;
        walker_fast4<32><<<wg, wb, 0, stream>>>(choices, out, n, h, epoch,
                                                adj_nodes, adj_offset, degrees);
    } else {
        int block = 256, grid = (n + block - 1) / block;
        walker_generic<<<grid, block, 0, stream>>>(adj_nodes, adj_offset,
                                                   degrees, choices, out, n, steps);
    }
}